// Round 4
// baseline (326.023 us; speedup 1.0000x reference)
//
#include <hip/hip_runtime.h>
#include <hip/hip_bf16.h>
#include <math.h>

// Problem constants
#define TDIM 4096
#define CDIM 256
#define BDIM 8
#define NTOK (BDIM * TDIM)   // 32768 rows
#define HIDDIM 1024
#define NCHUNK 64
#define CHLEN 64             // 4096 / 64

typedef float f32x4 __attribute__((ext_vector_type(4)));
typedef __bf16 bf16x8 __attribute__((ext_vector_type(8)));
typedef __bf16 bf16x4 __attribute__((ext_vector_type(4)));

// async global->LDS, 16 B/lane, lands at wave-uniform base + lane*16
#define GLDS16(gp, lp) __builtin_amdgcn_global_load_lds( \
    (const __attribute__((address_space(1))) void*)(gp), \
    (__attribute__((address_space(3))) void*)(lp), 16, 0, 0)

// s_waitcnt imm: vmcnt[3:0]|expcnt[6:4]|lgkmcnt[11:8]|vmcnt_hi[15:14]
#define WAITCNT_VM8 0x0F78   // vmcnt<=8, lgkm/exp unconstrained
#define WAITCNT_VM0 0x0F70   // vmcnt==0

// ---------------------------------------------------------------------------
// Weight pack: fp32 [K,N] -> bf16 transposed [N,K].
// ---------------------------------------------------------------------------
__global__ __launch_bounds__(256) void pack_weights(
    const float* __restrict__ Wk, const float* __restrict__ Wv,
    const float* __restrict__ Wr, const float* __restrict__ Wo,
    const float* __restrict__ Wkf, const float* __restrict__ Wvf,
    const float* __restrict__ Wrf,
    __bf16* __restrict__ WkvrT, __bf16* __restrict__ WoT,
    __bf16* __restrict__ WkfT, __bf16* __restrict__ WvfT,
    __bf16* __restrict__ WrfT) {
  long long j = (long long)blockIdx.x * 256 + threadIdx.x;
  if (j < 196608) {  // WkvrT: [768][256]
    int n = (int)(j >> 8), k = (int)(j & 255);
    const float* src = (n < 256) ? Wk : (n < 512 ? Wv : Wr);
    WkvrT[j] = (__bf16)src[k * 256 + (n & 255)];
    return;
  }
  j -= 196608;
  if (j < 65536) { int n = (int)(j >> 8), k = (int)(j & 255);
    WoT[j] = (__bf16)Wo[k * 256 + n]; return; }
  j -= 65536;
  if (j < 262144) { int n = (int)(j >> 8), k = (int)(j & 255);   // WkfT [1024][256]
    WkfT[j] = (__bf16)Wkf[(long long)k * 1024 + n]; return; }
  j -= 262144;
  if (j < 262144) { int n = (int)(j >> 10), k = (int)(j & 1023); // WvfT [256][1024]
    WvfT[j] = (__bf16)Wvf[(long long)k * 256 + n]; return; }
  j -= 262144;
  if (j < 65536) { int n = (int)(j >> 8), k = (int)(j & 255);
    WrfT[j] = (__bf16)Wrf[k * 256 + n]; return; }
}

// ---------------------------------------------------------------------------
// LayerNorm over C=256, one block per row, bf16 output.
// ---------------------------------------------------------------------------
__global__ __launch_bounds__(256) void ln_kernel(
    const float* __restrict__ x, const float* __restrict__ gamma,
    const float* __restrict__ beta, __bf16* __restrict__ h) {
  __shared__ float red[8];
  const long long row = blockIdx.x;
  const int tid = threadIdx.x;
  float v = x[row * CDIM + tid];
  float s = v, s2 = v * v;
  #pragma unroll
  for (int o = 1; o < 64; o <<= 1) { s += __shfl_xor(s, o); s2 += __shfl_xor(s2, o); }
  const int wave = tid >> 6, lane = tid & 63;
  if (lane == 0) { red[wave] = s; red[4 + wave] = s2; }
  __syncthreads();
  s = red[0] + red[1] + red[2] + red[3];
  s2 = red[4] + red[5] + red[6] + red[7];
  const float mean = s * (1.0f / CDIM);
  const float var = s2 * (1.0f / CDIM) - mean * mean;
  const float rstd = rsqrtf(var + 1e-5f);
  h[row * CDIM + tid] = (__bf16)((v - mean) * rstd * gamma[tid] + beta[tid]);
}

// ---------------------------------------------------------------------------
// Weight-stationary bf16 MFMA GEMM:  C[M,N] = A[M,K] * Bt[N,K]^T
// Block = 4 waves stacked in M (256 rows), each wave 64 x BN.
// B-panel (BN x 256k) staged in LDS ONCE per 256-k chunk (k-chunk XOR-swizzled
// in 16B units to kill bank conflicts); A streamed straight from global into
// MFMA fragments -> ZERO barriers in the k-step loop. Multi-chunk (K=1024)
// double-buffers chunks: 2 barriers per 8 k-steps.
// Accumulator TRANSPOSED (mfma(fb,fa)): lane holds 4 consecutive COLUMNS.
// Epilogues: 0 bf16=acc | 1 f32=src+acc | 2 bf16=relu(acc)^2
//            3 bf16=sigmoid(acc) | 4 f32=src+gate*acc
// ---------------------------------------------------------------------------
template <int BN, int NCHK, int EPI>
__global__ __launch_bounds__(256, (BN == 128 || NCHK > 1) ? 2 : 3)
void gemm2(const __bf16* __restrict__ A, const __bf16* __restrict__ Bt,
           int M, int N, int K,
           float* __restrict__ outF, __bf16* __restrict__ outH,
           const float* __restrict__ src, const __bf16* __restrict__ gate) {
  constexpr int NT = BN / 16;       // n-tiles per wave (wave spans whole BN)
  constexpr int NCALL = BN / 8;     // GLDS16 calls per chunk per thread
  constexpr int NBUF = (NCHK > 1) ? 2 : 1;
  __shared__ __bf16 sB[NBUF][BN * 256];   // [n][k] rows of 256 k-elems (512 B)

  const int tid = threadIdx.x;
  const int wave = tid >> 6, lane = tid & 63;
  const int quad = lane >> 4, mrow = lane & 15;
  const int m7 = mrow & 7;
  const long long m0 = (long long)blockIdx.x * 256 + wave * 64;
  const long long bn = (long long)blockIdx.y * BN;

  // ---- B staging: 16B chunk j of a row n holds global k-chunk (j&31)^(n&7).
  // Swizzle applied on the SOURCE address so GLDS16's dest stays contiguous.
  auto stage = [&](int c) {
    const int buf = c & (NBUF - 1);
    const long long kc = (long long)c * 256;
    #pragma unroll
    for (int i = 0; i < NCALL; i++) {
      const int j = i * 256 + tid;      // 16B-chunk index in panel
      const int n = j >> 5;             // 32 chunks per 512B row
      const int g = (j & 31) ^ (n & 7); // source k-chunk
      GLDS16(Bt + (bn + n) * (long long)K + kc + g * 8,
             &sB[buf][(long long)(i * 256 + wave * 64) * 8]);
    }
  };

  f32x4 acc[4][NT] = {};

  const __bf16* pA[4];
  #pragma unroll
  for (int mt = 0; mt < 4; mt++)
    pA[mt] = A + (m0 + mt * 16 + mrow) * (long long)K + quad * 8;

  stage(0);
  if (NCHK == 1) __syncthreads();

  #pragma unroll 1
  for (int c = 0; c < NCHK; c++) {
    if (NCHK > 1) {
      if (c + 1 < NCHK) {
        stage(c + 1);
        __builtin_amdgcn_s_waitcnt(WAITCNT_VM8);  // oldest (stage c) retired
      } else {
        __builtin_amdgcn_s_waitcnt(WAITCNT_VM0);
      }
      __builtin_amdgcn_s_barrier();
    }
    const int buf = c & (NBUF - 1);
    const long long kc = (long long)c * 256;
    #pragma unroll 2
    for (int s = 0; s < 8; s++) {           // 8 k-steps of 32
      bf16x8 fa[4], fb[NT];
      #pragma unroll
      for (int mt = 0; mt < 4; mt++)
        fa[mt] = *(const bf16x8*)(pA[mt] + kc + s * 32);
      #pragma unroll
      for (int nt = 0; nt < NT; nt++) {
        const int n = nt * 16 + mrow;
        const int p = (s * 4 + quad) ^ m7;  // de-swizzle
        fb[nt] = *(const bf16x8*)&sB[buf][n * 256 + p * 8];
      }
      #pragma unroll
      for (int mt = 0; mt < 4; mt++)
        #pragma unroll
        for (int nt = 0; nt < NT; nt++)
          acc[mt][nt] = __builtin_amdgcn_mfma_f32_16x16x32_bf16(fb[nt], fa[mt], acc[mt][nt], 0, 0, 0);
    }
    if (NCHK > 1 && c + 1 < NCHK) __builtin_amdgcn_s_barrier();  // readers done
  }

  // Transposed C/D: lane (quad,mrow) reg r -> row = m-tile+mrow,
  // col = n-tile + quad*4 + r  (4 consecutive cols per lane).
  #pragma unroll
  for (int mt = 0; mt < 4; mt++) {
    #pragma unroll
    for (int nt = 0; nt < NT; nt++) {
      const long long row = m0 + mt * 16 + mrow;
      const long long colb = bn + nt * 16 + quad * 4;
      const long long idx = row * N + colb;
      const f32x4 a = acc[mt][nt];
      if (EPI == 0) {
        bf16x4 o; o[0] = (__bf16)a[0]; o[1] = (__bf16)a[1];
        o[2] = (__bf16)a[2]; o[3] = (__bf16)a[3];
        *(bf16x4*)&outH[idx] = o;
      } else if (EPI == 1) {
        *(f32x4*)&outF[idx] = *(const f32x4*)&src[idx] + a;
      } else if (EPI == 2) {
        bf16x4 o;
        #pragma unroll
        for (int r = 0; r < 4; r++) { float t = a[r] > 0.0f ? a[r] : 0.0f; o[r] = (__bf16)(t * t); }
        *(bf16x4*)&outH[idx] = o;
      } else if (EPI == 3) {
        bf16x4 o;
        #pragma unroll
        for (int r = 0; r < 4; r++) o[r] = (__bf16)(1.0f / (1.0f + __expf(-a[r])));
        *(bf16x4*)&outH[idx] = o;
      } else {
        const f32x4 s4 = *(const f32x4*)&src[idx];
        const bf16x4 g4 = *(const bf16x4*)&gate[idx];
        f32x4 o;
        #pragma unroll
        for (int r = 0; r < 4; r++) o[r] = s4[r] + (float)g4[r] * a[r];
        *(f32x4*)&outF[idx] = o;
      }
    }
  }
}

// ---------------------------------------------------------------------------
// WKV chunked scan (direct fp32 recurrence; exponents bounded: |w*T|<=5,
// |k|~O(2), u~0).  S' = e^w S + e^k v ; y = (S + e^{u+k} v)/(Z + e^{u+k})
// ---------------------------------------------------------------------------
__global__ __launch_bounds__(256) void wkv_phase1(
    const __bf16* __restrict__ kvr, const float* __restrict__ decay,
    float* __restrict__ Sloc, float* __restrict__ Zloc) {
  const int c = threadIdx.x;
  const int chunk = blockIdx.x & (NCHUNK - 1);
  const int b = blockIdx.x >> 6;
  const float w = decay[c] * (1.0f / TDIM);
  const float ew = __expf(w);
  float S = 0.0f, Z = 0.0f;
  long long base = ((long long)b * TDIM + (long long)chunk * CHLEN) * 768 + c;
  for (int t = 0; t < CHLEN; t++) {
    float kt = (float)kvr[base + (long long)t * 768];
    float vt = (float)kvr[base + (long long)t * 768 + 256];
    float ek = __expf(kt);
    S = ew * S + ek * vt;
    Z = ew * Z + ek;
  }
  long long o = ((long long)b * NCHUNK + chunk) * CDIM + c;
  Sloc[o] = S;
  Zloc[o] = Z;
}

__global__ __launch_bounds__(256) void wkv_phase2(
    const float* __restrict__ Sloc, const float* __restrict__ Zloc,
    const float* __restrict__ decay,
    float* __restrict__ Sstart, float* __restrict__ Zstart) {
  const int idx = blockIdx.x * 256 + threadIdx.x;  // 0..2047
  const int c = idx & 255;
  const int b = idx >> 8;
  const float w = decay[c] * (1.0f / TDIM);
  const float ewL = __expf(w * (float)CHLEN);
  float S = 0.0f, Z = 0.0f;
  for (int j = 0; j < NCHUNK; j++) {
    long long o = ((long long)b * NCHUNK + j) * CDIM + c;
    Sstart[o] = S;
    Zstart[o] = Z;
    S = ewL * S + Sloc[o];
    Z = ewL * Z + Zloc[o];
  }
}

__global__ __launch_bounds__(256) void wkv_phase3(
    const __bf16* __restrict__ kvr, const float* __restrict__ decay,
    const float* __restrict__ first, const float* __restrict__ Sstart,
    const float* __restrict__ Zstart, __bf16* __restrict__ a2) {
  const int c = threadIdx.x;
  const int chunk = blockIdx.x & (NCHUNK - 1);
  const int b = blockIdx.x >> 6;
  const float w = decay[c] * (1.0f / TDIM);
  const float u = first[c] * (1.0f / TDIM);
  const float ew = __expf(w);
  const float eu = __expf(u);
  long long so = ((long long)b * NCHUNK + chunk) * CDIM + c;
  float S = Sstart[so], Z = Zstart[so];
  long long base = ((long long)b * TDIM + (long long)chunk * CHLEN) * 768 + c;
  long long obase = ((long long)b * TDIM + (long long)chunk * CHLEN) * CDIM + c;
  for (int t = 0; t < CHLEN; t++) {
    float kt = (float)kvr[base + (long long)t * 768];
    float vt = (float)kvr[base + (long long)t * 768 + 256];
    float rt = (float)kvr[base + (long long)t * 768 + 512];
    float ek = __expf(kt);
    float E = eu * ek;
    float y = (S + E * vt) / (Z + E);
    float sr = 1.0f / (1.0f + __expf(-rt));
    a2[obase + (long long)t * CDIM] = (__bf16)(sr * y);
    S = ew * S + ek * vt;
    Z = ew * Z + ek;
  }
}

// ---------------------------------------------------------------------------
// Workspace layout (peak ~170.5 MB):
//   [0)       h (bf16, 16 MB)     -> reused as a2, then g2buf
//   [16 MB)   kvr (bf16, 48 MB)   -> first 16 MB reused as h2
//   [64 MB)   x1 (f32, 32 MB)
//   [96 MB)   scan state (2 MB, dead before EPI2) then kk (bf16, 64 MB)
//   [160 MB)  packed bf16 weights (~1.7 MB)
// ---------------------------------------------------------------------------
extern "C" void kernel_launch(void* const* d_in, const int* in_sizes, int n_in,
                              void* d_out, int out_size, void* d_ws, size_t ws_size,
                              hipStream_t stream) {
  const float* x     = (const float*)d_in[0];
  const float* Wk    = (const float*)d_in[1];
  const float* Wv    = (const float*)d_in[2];
  const float* Wr    = (const float*)d_in[3];
  const float* Wo    = (const float*)d_in[4];
  const float* Wkf   = (const float*)d_in[5];
  const float* Wvf   = (const float*)d_in[6];
  const float* Wrf   = (const float*)d_in[7];
  const float* g1    = (const float*)d_in[8];
  const float* b1    = (const float*)d_in[9];
  const float* g2    = (const float*)d_in[10];
  const float* b2    = (const float*)d_in[11];
  const float* decay = (const float*)d_in[12];
  const float* first = (const float*)d_in[13];
  float* out = (float*)d_out;
  char* ws = (char*)d_ws;

  __bf16* hbuf   = (__bf16*)(ws + 0);               // h -> a2 -> g2buf
  __bf16* kvr    = (__bf16*)(ws + 16777216LL);
  __bf16* h2     = (__bf16*)(ws + 16777216LL);      // aliases kvr (dead by then)
  float*  x1     = (float*)(ws + 67108864LL);
  float*  Sloc   = (float*)(ws + 100663296LL);      // scan state: dead before kk
  float*  Zloc   = (float*)(ws + 101187584LL);
  float*  Sstart = (float*)(ws + 101711872LL);
  float*  Zstart = (float*)(ws + 102236160LL);
  __bf16* kk     = (__bf16*)(ws + 100663296LL);     // overwrites scan state (safe)
  __bf16* WkvrT  = (__bf16*)(ws + 167772160LL);
  __bf16* WoT    = (__bf16*)(ws + 168165376LL);
  __bf16* WkfT   = (__bf16*)(ws + 168296448LL);
  __bf16* WvfT   = (__bf16*)(ws + 168820736LL);
  __bf16* WrfT   = (__bf16*)(ws + 169345024LL);

  pack_weights<<<3328, 256, 0, stream>>>(Wk, Wv, Wr, Wo, Wkf, Wvf, Wrf,
                                         WkvrT, WoT, WkfT, WvfT, WrfT);

  // --- SpatialMix ---
  ln_kernel<<<NTOK, 256, 0, stream>>>(x, g1, b1, hbuf);
  gemm2<128, 1, 0><<<dim3(NTOK / 256, 768 / 128), 256, 0, stream>>>(
      hbuf, WkvrT, NTOK, 768, CDIM, nullptr, kvr, nullptr, nullptr);
  wkv_phase1<<<BDIM * NCHUNK, 256, 0, stream>>>(kvr, decay, Sloc, Zloc);
  wkv_phase2<<<BDIM, 256, 0, stream>>>(Sloc, Zloc, decay, Sstart, Zstart);
  wkv_phase3<<<BDIM * NCHUNK, 256, 0, stream>>>(kvr, decay, first, Sstart, Zstart, hbuf);
  gemm2<64, 1, 1><<<dim3(NTOK / 256, CDIM / 64), 256, 0, stream>>>(
      hbuf, WoT, NTOK, CDIM, CDIM, x1, nullptr, x, nullptr);

  // --- ChannelMix ---
  ln_kernel<<<NTOK, 256, 0, stream>>>(x1, g2, b2, h2);
  gemm2<128, 1, 2><<<dim3(NTOK / 256, HIDDIM / 128), 256, 0, stream>>>(
      h2, WkfT, NTOK, HIDDIM, CDIM, nullptr, kk, nullptr, nullptr);
  gemm2<64, 1, 3><<<dim3(NTOK / 256, CDIM / 64), 256, 0, stream>>>(
      h2, WrfT, NTOK, CDIM, CDIM, nullptr, hbuf, nullptr, nullptr);   // g2buf = hbuf
  gemm2<64, 4, 4><<<dim3(NTOK / 256, CDIM / 64), 256, 0, stream>>>(
      kk, WvfT, NTOK, CDIM, HIDDIM, out, nullptr, x1, hbuf);
}

// Round 5
// 280.866 us; speedup vs baseline: 1.1608x; 1.1608x over previous
//
#include <hip/hip_runtime.h>
#include <hip/hip_bf16.h>
#include <math.h>

// Problem constants
#define TDIM 4096
#define CDIM 256
#define BDIM 8
#define NTOK (BDIM * TDIM)   // 32768 rows
#define HIDDIM 1024
#define NCHUNK 128
#define CHLEN 32             // 4096 / 128

typedef float f32x4 __attribute__((ext_vector_type(4)));
typedef __bf16 bf16x8 __attribute__((ext_vector_type(8)));
typedef __bf16 bf16x4 __attribute__((ext_vector_type(4)));

// async global->LDS, 16 B/lane, lands at wave-uniform base + lane*16
#define GLDS16(gp, lp) __builtin_amdgcn_global_load_lds( \
    (const __attribute__((address_space(1))) void*)(gp), \
    (__attribute__((address_space(3))) void*)(lp), 16, 0, 0)

// s_waitcnt imm: vmcnt[3:0]|expcnt[6:4]|lgkmcnt[11:8]|vmcnt_hi[15:14]
#define WAITCNT_VM6 0x0F76
#define WAITCNT_VM4 0x0F74
#define WAITCNT_VM0 0x0F70

__device__ __forceinline__ float sigm(float v) { return 1.0f / (1.0f + __expf(-v)); }

// ---------------------------------------------------------------------------
// Weight pack: fp32 [K,N] -> bf16 transposed [N,K].
//   WkvrT [768][256] = [Wk^T; Wv^T; Wr^T]
//   WoT   [256][256]
//   Wkfr  [1280][256] = [Wkf^T; Wrf^T]
//   WvfT  [256][1024]
// ---------------------------------------------------------------------------
__global__ __launch_bounds__(256) void pack_weights(
    const float* __restrict__ Wk, const float* __restrict__ Wv,
    const float* __restrict__ Wr, const float* __restrict__ Wo,
    const float* __restrict__ Wkf, const float* __restrict__ Wvf,
    const float* __restrict__ Wrf,
    __bf16* __restrict__ WkvrT, __bf16* __restrict__ WoT,
    __bf16* __restrict__ Wkfr, __bf16* __restrict__ WvfT) {
  long long j = (long long)blockIdx.x * 256 + threadIdx.x;
  if (j < 196608) {
    int n = (int)(j >> 8), k = (int)(j & 255);
    const float* src = (n < 256) ? Wk : (n < 512 ? Wv : Wr);
    WkvrT[j] = (__bf16)src[k * 256 + (n & 255)];
    return;
  }
  j -= 196608;
  if (j < 65536) { int n = (int)(j >> 8), k = (int)(j & 255);
    WoT[j] = (__bf16)Wo[k * 256 + n]; return; }
  j -= 65536;
  if (j < 327680) { int n = (int)(j >> 8), k = (int)(j & 255);
    Wkfr[j] = (__bf16)(n < 1024 ? Wkf[(long long)k * 1024 + n]
                                : Wrf[k * 256 + (n - 1024)]);
    return; }
  j -= 327680;
  if (j < 262144) { int n = (int)(j >> 10), k = (int)(j & 1023);
    WvfT[j] = (__bf16)Wvf[(long long)k * 256 + n]; return; }
}

// ---------------------------------------------------------------------------
// LayerNorm over C=256: one wave per row, 4 rows/block, float4/bf16x4 loads.
// ---------------------------------------------------------------------------
template <typename T>
__global__ __launch_bounds__(256) void ln_kernel(
    const T* __restrict__ x, const float* __restrict__ gamma,
    const float* __restrict__ beta, __bf16* __restrict__ h) {
  const int wave = threadIdx.x >> 6, lane = threadIdx.x & 63;
  const long long row = (long long)blockIdx.x * 4 + wave;
  const long long base = row * CDIM + lane * 4;
  f32x4 v;
  if constexpr (sizeof(T) == 4) {
    v = *(const f32x4*)&x[base];
  } else {
    bf16x4 t = *(const bf16x4*)&x[base];
    v[0] = (float)t[0]; v[1] = (float)t[1]; v[2] = (float)t[2]; v[3] = (float)t[3];
  }
  float s = v[0] + v[1] + v[2] + v[3];
  float s2 = v[0]*v[0] + v[1]*v[1] + v[2]*v[2] + v[3]*v[3];
  #pragma unroll
  for (int o = 1; o < 64; o <<= 1) { s += __shfl_xor(s, o); s2 += __shfl_xor(s2, o); }
  const float mean = s * (1.0f / CDIM);
  const float var = s2 * (1.0f / CDIM) - mean * mean;
  const float rstd = rsqrtf(var + 1e-5f);
  const f32x4 g4 = *(const f32x4*)&gamma[lane * 4];
  const f32x4 b4 = *(const f32x4*)&beta[lane * 4];
  bf16x4 o;
  #pragma unroll
  for (int r = 0; r < 4; r++) o[r] = (__bf16)((v[r] - mean) * rstd * g4[r] + b4[r]);
  *(bf16x4*)&h[base] = o;
}

// ---------------------------------------------------------------------------
// Pipelined bf16 MFMA GEMM (round-3 structure, parametrized wave tile).
//   C[M,N] = A[M,K] * Bt[N,K]^T
// BM=128, BN in {128,256}; 4 waves as 2(m) x 2(n): wave tile 64 x BN/2.
// Triple-buffered LDS, prefetch distance 2, raw s_barrier + partial vmcnt.
// Accumulator TRANSPOSED (mfma(fb,fa)): lane (quad,mrow) reg r ->
//   row = mtile+mrow, col = ntile + quad*4 + r (4 consecutive cols/lane).
// EPI 0: planar kvr store (y=0:k, 1:v, 2:sigmoid->r), plane stride M*256
// EPI 1: bf16 out = f32 src + acc                   (x1h)
// EPI 2: y<4: kk = relu(acc)^2 [stride 1024] ; y==4: g2 = sigmoid [stride 256]
// EPI 3: f32 out = (f32)srcH + (f32)gate * acc      (final)
// ---------------------------------------------------------------------------
template <int BN, int EPI>
__global__ __launch_bounds__(256, 2) void gemm3(
    const __bf16* __restrict__ A, const __bf16* __restrict__ Bt,
    int M, int N, int K,
    float* __restrict__ outF, __bf16* __restrict__ outH,
    __bf16* __restrict__ outH2,
    const float* __restrict__ srcF, const __bf16* __restrict__ srcH,
    const __bf16* __restrict__ gate) {
  constexpr int WNT = BN / 32;        // n-tiles per wave
  constexpr int NBC = BN / 64;        // B staging calls per wave
  __shared__ __bf16 sA[3][128 * 32];
  __shared__ __bf16 sB[3][BN * 32];

  const int tid = threadIdx.x;
  const int wave = tid >> 6, lane = tid & 63;
  const int quad = lane >> 4, mrow = lane & 15;
  const long long bm = (long long)blockIdx.x * 128;
  const long long bn = (long long)blockIdx.y * BN;
  const int wm = (wave & 1) * 64, wn = (wave >> 1) * (BN / 2);

  const int lrow = lane >> 2;          // 0..15
  const int lk = (lane & 3) * 8;       // 0,8,16,24

  auto issue = [&](int g) {
    const int buf = g % 3;
    const long long k0 = (long long)g * 32;
    const int a0 = wave * 32;
    GLDS16(A + (bm + a0 + lrow) * (long long)K + k0 + lk, &sA[buf][a0 * 32]);
    GLDS16(A + (bm + a0 + 16 + lrow) * (long long)K + k0 + lk, &sA[buf][(a0 + 16) * 32]);
    #pragma unroll
    for (int bc = 0; bc < NBC; bc++) {
      const int r0 = wave * (BN / 4) + bc * 16;
      GLDS16(Bt + (bn + r0 + lrow) * (long long)K + k0 + lk, &sB[buf][r0 * 32]);
    }
  };

  f32x4 acc[4][WNT] = {};

  const int nit = K / 32;
  issue(0);
  issue(1);

  auto compute = [&](int i) {
    const int buf = i % 3;
    bf16x8 fa[4], fb[WNT];
    #pragma unroll
    for (int mt = 0; mt < 4; mt++)
      fa[mt] = *(const bf16x8*)&sA[buf][(wm + mt * 16 + mrow) * 32 + quad * 8];
    #pragma unroll
    for (int nt = 0; nt < WNT; nt++)
      fb[nt] = *(const bf16x8*)&sB[buf][(wn + nt * 16 + mrow) * 32 + quad * 8];
    #pragma unroll
    for (int mt = 0; mt < 4; mt++)
      #pragma unroll
      for (int nt = 0; nt < WNT; nt++)
        acc[mt][nt] = __builtin_amdgcn_mfma_f32_16x16x32_bf16(fb[nt], fa[mt], acc[mt][nt], 0, 0, 0);
  };

  #pragma unroll 1
  for (int i = 0; i < nit - 1; i++) {
    __builtin_amdgcn_s_waitcnt(BN == 256 ? WAITCNT_VM6 : WAITCNT_VM4);
    __builtin_amdgcn_s_barrier();
    if (i + 2 < nit) issue(i + 2);
    compute(i);
  }
  __builtin_amdgcn_s_waitcnt(WAITCNT_VM0);
  __builtin_amdgcn_s_barrier();
  compute(nit - 1);

  #pragma unroll
  for (int mt = 0; mt < 4; mt++) {
    #pragma unroll
    for (int nt = 0; nt < WNT; nt++) {
      const long long row = bm + wm + mt * 16 + mrow;
      const int cloc = wn + nt * 16 + quad * 4;     // col within block tile
      const long long colb = bn + cloc;
      const f32x4 a = acc[mt][nt];
      if (EPI == 0) {
        // planar: plane = blockIdx.y; y==2 -> sigmoid (receptance)
        __bf16* o = outH + (long long)blockIdx.y * ((long long)M * 256);
        bf16x4 v;
        if (blockIdx.y == 2) {
          #pragma unroll
          for (int r = 0; r < 4; r++) v[r] = (__bf16)sigm(a[r]);
        } else {
          #pragma unroll
          for (int r = 0; r < 4; r++) v[r] = (__bf16)a[r];
        }
        *(bf16x4*)&o[row * 256 + cloc] = v;
      } else if (EPI == 1) {
        const long long idx = row * N + colb;
        const f32x4 s4 = *(const f32x4*)&srcF[idx];
        bf16x4 v;
        #pragma unroll
        for (int r = 0; r < 4; r++) v[r] = (__bf16)(s4[r] + a[r]);
        *(bf16x4*)&outH[idx] = v;
      } else if (EPI == 2) {
        if (blockIdx.y < 4) {
          bf16x4 v;
          #pragma unroll
          for (int r = 0; r < 4; r++) { float t = a[r] > 0.0f ? a[r] : 0.0f; v[r] = (__bf16)(t * t); }
          *(bf16x4*)&outH[row * 1024 + colb] = v;
        } else {
          bf16x4 v;
          #pragma unroll
          for (int r = 0; r < 4; r++) v[r] = (__bf16)sigm(a[r]);
          *(bf16x4*)&outH2[row * 256 + (colb - 1024)] = v;
        }
      } else {
        const long long idx = row * N + colb;
        const bf16x4 s4 = *(const bf16x4*)&srcH[idx];
        const bf16x4 g4 = *(const bf16x4*)&gate[idx];
        f32x4 v;
        #pragma unroll
        for (int r = 0; r < 4; r++) v[r] = (float)s4[r] + (float)g4[r] * a[r];
        *(f32x4*)&outF[idx] = v;
      }
    }
  }
}

// ---------------------------------------------------------------------------
// WKV chunked scan on planar k/v/sr arrays. Direct fp32 recurrence (exponents
// bounded: |w*T|<=5, |k|~O(2), u~0). One wave per (b,chunk); lane owns 4
// channels -> bf16x4 loads (8 B/lane).
// ---------------------------------------------------------------------------
__global__ __launch_bounds__(256) void wkv_phase1(
    const __bf16* __restrict__ ka, const __bf16* __restrict__ va,
    const float* __restrict__ decay,
    float* __restrict__ Sloc, float* __restrict__ Zloc) {
  const int wave = threadIdx.x >> 6, lane = threadIdx.x & 63;
  const int gi = blockIdx.x * 4 + wave;          // 0..1023
  const int b = gi >> 7, chunk = gi & (NCHUNK - 1);
  const int c0 = lane * 4;
  const f32x4 w4 = *(const f32x4*)&decay[c0];
  f32x4 ew;
  #pragma unroll
  for (int r = 0; r < 4; r++) ew[r] = __expf(w4[r] * (1.0f / TDIM));
  f32x4 S = {0,0,0,0}, Z = {0,0,0,0};
  long long base = ((long long)b * TDIM + (long long)chunk * CHLEN) * 256 + c0;
  #pragma unroll 4
  for (int t = 0; t < CHLEN; t++) {
    const bf16x4 k4 = *(const bf16x4*)&ka[base + (long long)t * 256];
    const bf16x4 v4 = *(const bf16x4*)&va[base + (long long)t * 256];
    #pragma unroll
    for (int r = 0; r < 4; r++) {
      const float ek = __expf((float)k4[r]);
      S[r] = ew[r] * S[r] + ek * (float)v4[r];
      Z[r] = ew[r] * Z[r] + ek;
    }
  }
  const long long o = (long long)gi * 256 + c0;
  *(f32x4*)&Sloc[o] = S;
  *(f32x4*)&Zloc[o] = Z;
}

__global__ __launch_bounds__(256) void wkv_phase2(
    const float* __restrict__ Sloc, const float* __restrict__ Zloc,
    const float* __restrict__ decay,
    float* __restrict__ Sstart, float* __restrict__ Zstart) {
  const int idx = blockIdx.x * 256 + threadIdx.x;  // 0..2047
  const int c = idx & 255;
  const int b = idx >> 8;
  const float w = decay[c] * (1.0f / TDIM);
  const float ewL = __expf(w * (float)CHLEN);
  float S = 0.0f, Z = 0.0f;
  for (int j = 0; j < NCHUNK; j++) {
    const long long o = ((long long)b * NCHUNK + j) * 256 + c;
    Sstart[o] = S;
    Zstart[o] = Z;
    S = ewL * S + Sloc[o];
    Z = ewL * Z + Zloc[o];
  }
}

__global__ __launch_bounds__(256) void wkv_phase3(
    const __bf16* __restrict__ ka, const __bf16* __restrict__ va,
    const __bf16* __restrict__ ra,   // holds sigmoid(r)
    const float* __restrict__ decay, const float* __restrict__ first,
    const float* __restrict__ Sstart, const float* __restrict__ Zstart,
    __bf16* __restrict__ a2) {
  const int wave = threadIdx.x >> 6, lane = threadIdx.x & 63;
  const int gi = blockIdx.x * 4 + wave;
  const int b = gi >> 7, chunk = gi & (NCHUNK - 1);
  const int c0 = lane * 4;
  const f32x4 w4 = *(const f32x4*)&decay[c0];
  const f32x4 u4 = *(const f32x4*)&first[c0];
  f32x4 ew, eu;
  #pragma unroll
  for (int r = 0; r < 4; r++) {
    ew[r] = __expf(w4[r] * (1.0f / TDIM));
    eu[r] = __expf(u4[r] * (1.0f / TDIM));
  }
  const long long so = (long long)gi * 256 + c0;
  f32x4 S = *(const f32x4*)&Sstart[so];
  f32x4 Z = *(const f32x4*)&Zstart[so];
  long long base = ((long long)b * TDIM + (long long)chunk * CHLEN) * 256 + c0;
  #pragma unroll 2
  for (int t = 0; t < CHLEN; t++) {
    const long long p = base + (long long)t * 256;
    const bf16x4 k4 = *(const bf16x4*)&ka[p];
    const bf16x4 v4 = *(const bf16x4*)&va[p];
    const bf16x4 r4 = *(const bf16x4*)&ra[p];
    bf16x4 o;
    #pragma unroll
    for (int r = 0; r < 4; r++) {
      const float ek = __expf((float)k4[r]);
      const float E = eu[r] * ek;
      const float y = (S[r] + E * (float)v4[r]) / (Z[r] + E);
      o[r] = (__bf16)((float)r4[r] * y);
      S[r] = ew[r] * S[r] + ek * (float)v4[r];
      Z[r] = ew[r] * Z[r] + ek;
    }
    *(bf16x4*)&a2[p] = o;
  }
}

// ---------------------------------------------------------------------------
// Workspace layout (peak ~161.6 MB):
//   [0)      ka (bf16 16 MB)         [16M)  va          [32M)  ra (=sigmoid r)
//   [48M)    a2 (16 MB) -> reused as h2
//   [64M)    h  (16 MB) -> reused as g2
//   [80M)    x1h (bf16 16 MB)
//   [96M)    scan state S/Z (4 MB, dead before kk) then kk (bf16 64 MB)
//   [160M)   packed weights (~1.7 MB)
// ---------------------------------------------------------------------------
extern "C" void kernel_launch(void* const* d_in, const int* in_sizes, int n_in,
                              void* d_out, int out_size, void* d_ws, size_t ws_size,
                              hipStream_t stream) {
  const float* x     = (const float*)d_in[0];
  const float* Wk    = (const float*)d_in[1];
  const float* Wv    = (const float*)d_in[2];
  const float* Wr    = (const float*)d_in[3];
  const float* Wo    = (const float*)d_in[4];
  const float* Wkf   = (const float*)d_in[5];
  const float* Wvf   = (const float*)d_in[6];
  const float* Wrf   = (const float*)d_in[7];
  const float* g1    = (const float*)d_in[8];
  const float* b1    = (const float*)d_in[9];
  const float* g2    = (const float*)d_in[10];
  const float* b2    = (const float*)d_in[11];
  const float* decay = (const float*)d_in[12];
  const float* first = (const float*)d_in[13];
  float* out = (float*)d_out;
  char* ws = (char*)d_ws;

  __bf16* ka     = (__bf16*)(ws + 0);
  __bf16* va     = (__bf16*)(ws + 16777216LL);
  __bf16* ra     = (__bf16*)(ws + 33554432LL);
  __bf16* a2     = (__bf16*)(ws + 50331648LL);
  __bf16* h2     = (__bf16*)(ws + 50331648LL);      // reuses a2 (dead)
  __bf16* hbuf   = (__bf16*)(ws + 67108864LL);
  __bf16* g2buf  = (__bf16*)(ws + 67108864LL);      // reuses h (dead)
  __bf16* x1h    = (__bf16*)(ws + 83886080LL);
  float*  Sloc   = (float*)(ws + 100663296LL);      // dead before kk written
  float*  Zloc   = (float*)(ws + 101711872LL);
  float*  Sstart = (float*)(ws + 102760448LL);
  float*  Zstart = (float*)(ws + 103809024LL);
  __bf16* kk     = (__bf16*)(ws + 100663296LL);     // overwrites scan state
  __bf16* WkvrT  = (__bf16*)(ws + 167772160LL);
  __bf16* WoT    = (__bf16*)(ws + 168165376LL);
  __bf16* Wkfr   = (__bf16*)(ws + 168296448LL);
  __bf16* WvfT   = (__bf16*)(ws + 168951808LL);

  pack_weights<<<3328, 256, 0, stream>>>(Wk, Wv, Wr, Wo, Wkf, Wvf, Wrf,
                                         WkvrT, WoT, Wkfr, WvfT);

  // --- SpatialMix ---
  ln_kernel<float><<<NTOK / 4, 256, 0, stream>>>(x, g1, b1, hbuf);
  gemm3<256, 0><<<dim3(NTOK / 128, 3), 256, 0, stream>>>(
      hbuf, WkvrT, NTOK, 768, CDIM, nullptr, ka, nullptr, nullptr, nullptr, nullptr);
  wkv_phase1<<<BDIM * NCHUNK / 4, 256, 0, stream>>>(ka, va, decay, Sloc, Zloc);
  wkv_phase2<<<BDIM, 256, 0, stream>>>(Sloc, Zloc, decay, Sstart, Zstart);
  wkv_phase3<<<BDIM * NCHUNK / 4, 256, 0, stream>>>(ka, va, ra, decay, first,
                                                    Sstart, Zstart, a2);
  gemm3<128, 1><<<dim3(NTOK / 128, 2), 256, 0, stream>>>(
      a2, WoT, NTOK, CDIM, CDIM, nullptr, x1h, nullptr, x, nullptr, nullptr);

  // --- ChannelMix ---
  ln_kernel<__bf16><<<NTOK / 4, 256, 0, stream>>>(x1h, g2, b2, h2);
  gemm3<256, 2><<<dim3(NTOK / 128, 5), 256, 0, stream>>>(
      h2, Wkfr, NTOK, 1280, CDIM, nullptr, kk, g2buf, nullptr, nullptr, nullptr);
  gemm3<128, 3><<<dim3(NTOK / 128, 2), 256, 0, stream>>>(
      kk, WvfT, NTOK, CDIM, HIDDIM, out, nullptr, nullptr, nullptr, x1h, g2buf);
}